// Round 14
// baseline (322.133 us; speedup 1.0000x reference)
//
#include <hip/hip_runtime.h>
#include <hip/hip_bf16.h>

// VQ argmin via MX-scaled fp8 (e4m3, scale=1.0) K=128 MFMA filter + exact
// fp64 refine. Round 14: kill the fragment-repack VALU. r12 proved the
// bank-conflict counter is layout-invariant (structural), so return to the
// r11 CONTIGUOUS-32B-per-lane layout and load each fragment as ONE i32x8
// (2x ds_read_b128 into consecutive regs, no shufflevector movs). A-side
// kp-dependence handled with two hoisted parity bases + literal +256.
// 12-phase unroll / VMW protocol / setprio / epilogue == round 13.
// Scratch carved from d_out[0:N*D) (float offsets):
//   Xq  fp8[N][512]   @ 0        (16 MiB)
//   Cq  fp8[K][512]   @ 4194304  ( 4 MiB)
//   cand int[N][96]   @ 5242880  (12 MiB)
// c2 f32[K] in d_ws.

constexpr int NTOK = 32768, DIM = 512, KCODES = 8192;
constexpr float MARGIN = 20.0f;

using ffrag = __attribute__((ext_vector_type(4))) float;   // 4 f32 acc
using i32x8 = __attribute__((ext_vector_type(8))) int;

#define GLD_LDS16(g, l)                                                        \
  __builtin_amdgcn_global_load_lds(                                            \
      (const __attribute__((address_space(1))) void*)(g),                      \
      (__attribute__((address_space(3))) void*)(l), 16, 0, 0)
#define VMW(N) asm volatile("s_waitcnt vmcnt(" #N ")" ::: "memory")

// ---- f32 -> fp8 e4m3fn, explicit RNE ---------------------------------------
__device__ __forceinline__ unsigned char f2e4m3(float x) {
  unsigned u = __float_as_uint(x);
  unsigned s = (u >> 24) & 0x80u;
  float ax = fabsf(x);
  if (ax < 0.015625f) {
    int q = (int)rintf(ax * 512.0f);
    return (unsigned char)(s | (unsigned)q);
  }
  int e = (int)((u >> 23) & 0xFF) - 127;
  float m = __uint_as_float((u & 0x7FFFFFu) | 0x3F800000u);
  int r = (int)rintf(m * 8.0f);
  if (r == 16) { r = 8; ++e; }
  if (e > 8) { e = 8; r = 15; }
  return (unsigned char)(s | ((unsigned)(e + 7) << 3) | (unsigned)(r - 8));
}

// ---- convert fp32 rows -> fp8, optional sum-of-squares ---------------------
__global__ void vq_prep8(const float* __restrict__ src, unsigned char* __restrict__ dst,
                         float* __restrict__ sq, int rows) {
  int w = (blockIdx.x * blockDim.x + threadIdx.x) >> 6;
  int lane = threadIdx.x & 63;
  if (w >= rows) return;
  const float4* r4 = (const float4*)(src + (size_t)w * DIM);
  float4 a = r4[lane * 2], b = r4[lane * 2 + 1];
  union { unsigned char c[8]; uint2 v; } o;
  o.c[0]=f2e4m3(a.x); o.c[1]=f2e4m3(a.y); o.c[2]=f2e4m3(a.z); o.c[3]=f2e4m3(a.w);
  o.c[4]=f2e4m3(b.x); o.c[5]=f2e4m3(b.y); o.c[6]=f2e4m3(b.z); o.c[7]=f2e4m3(b.w);
  *(uint2*)(dst + (size_t)w * DIM + lane * 8) = o.v;
  if (sq != nullptr) {
    float s = a.x*a.x + a.y*a.y + a.z*a.z + a.w*a.w
            + b.x*b.x + b.y*b.y + b.z*b.z + b.w*b.w;
    #pragma unroll
    for (int off = 32; off; off >>= 1) s += __shfl_down(s, off, 64);
    if (lane == 0) sq[w] = s;
  }
}

// ---- fused MX-fp8 K=128 MFMA distance + best-3 + candidate emission --------
// Block: 256 thr (4 waves: wr,wc in {0,1}), 64 rows x FULL 8192 codes.
// As [64 rows][16 blocks of 32B], block j stored at j^(row&7) (halves in
// order). Slab ring-3 [128 cols][4 blocks of 32B], block stored at b^(col&3).
// Lane's 32 logical k-bytes (one MX scale block) are CONTIGUOUS -> one i32x8.
__launch_bounds__(256, 2)
__global__ void vq_main(const unsigned char* __restrict__ Xq,
                        const unsigned char* __restrict__ Cq,
                        const float* __restrict__ c2g, int* __restrict__ cand) {
  __shared__ __align__(32) unsigned char As[64 * 512];     // 32 KiB
  __shared__ __align__(32) unsigned char Bs[3][16384];     // 48 KiB ring-3
  const int tid = threadIdx.x, lane = tid & 63;
  const int wid = tid >> 6, wr = wid >> 1, wc = wid & 1;
  const int row0 = blockIdx.x * 64;
  const int l15 = lane & 15, l4 = lane >> 4;

  // ---------- prologue staging (pair-swizzled sources, r11 formulas) --------
  #pragma unroll
  for (int it = 0; it < 8; ++it) {
    int p = it * 256 + tid, rA = p >> 5, u = p & 31;
    GLD_LDS16(Xq + (size_t)(row0 + rA) * DIM +
                  ((((u >> 1) ^ (rA & 7)) << 5) | ((u & 1) << 4)),
              &As[0] + p * 16);
  }
  #pragma unroll
  for (int t0 = 0; t0 < 2; ++t0) {
    #pragma unroll
    for (int i = 0; i < 4; ++i) {
      int p = i * 256 + tid, c = p >> 3, u = p & 7;
      GLD_LDS16(Cq + (size_t)c * DIM + t0 * 128 +
                    ((((u >> 1) ^ (c & 3)) << 5) | ((u & 1) << 4)),
                &Bs[t0][0] + p * 16);
    }
  }
  VMW(4);                                  // As + slab0 landed (slab1 flying)
  __builtin_amdgcn_s_barrier();

  // ---------- hoisted per-thread address state ----------
  // A block j = kp*4+l4; (j^sw) = ((kp&1)^swBit2)<<2 | (kp>>1)<<3 | (l4^(sw&3))
  int aB0[2], aB1[2];
  #pragma unroll
  for (int rf = 0; rf < 2; ++rf) {
    int rA = wr * 32 + rf * 16 + l15, sw = rA & 7;
    int base = rA * 512 + ((l4 ^ (sw & 3)) << 5);
    aB0[rf] = base + (((sw >> 2) & 1) << 7);        // kp even
    aB1[rf] = base + ((((sw >> 2) ^ 1) & 1) << 7);  // kp odd
  }
  int bB[4];
  #pragma unroll
  for (int cf = 0; cf < 4; ++cf) {
    int rB = wc * 64 + cf * 16 + l15;
    bB[cf] = rB * 128 + ((l4 ^ (rB & 3)) << 5);
  }
  const int cS = tid >> 3, uS = tid & 7;
  const unsigned char* gsrc = Cq + cS * 512 +
      ((((uS >> 1) ^ (cS & 3)) << 5) | ((uS & 1) << 4)) + 256;   // ts=2
  const float* c2p = c2g + wc * 64 + l15;
  unsigned char* ldst = &Bs[0][0] + tid * 16;
  const unsigned char* AsP = &As[0];
  const unsigned char* BsP = &Bs[0][0];

  unsigned b0k[2][4], b1k[2][4], b2k[2][4];
  #pragma unroll
  for (int rf = 0; rf < 2; ++rf)
    #pragma unroll
    for (int rg = 0; rg < 4; ++rg) {
      b0k[rf][rg] = 0xFFFFFFFFu; b1k[rf][rg] = 0xFFFFFFFFu; b2k[rf][rg] = 0xFFFFFFFFu;
    }
  ffrag acc[2][4];
  float c2v[4];

// One phase. KP/RS/SS/GSTEP/VMN are literals; CT is a runtime int.
#define PH(KP, RS, SS, CT, STG, GSTEP, VMN)                                    \
  {                                                                            \
    if (KP == 2) {                                                             \
      c2v[0] = c2p[0]  + 2048.0f; c2v[1] = c2p[16] + 2048.0f;                  \
      c2v[2] = c2p[32] + 2048.0f; c2v[3] = c2p[48] + 2048.0f;                  \
      c2p += 128;                                                              \
    }                                                                          \
    if (STG) {                                                                 \
      GLD_LDS16(gsrc,         ldst + (SS) * 16384 + 0);                        \
      GLD_LDS16(gsrc + 16384, ldst + (SS) * 16384 + 4096);                     \
      GLD_LDS16(gsrc + 32768, ldst + (SS) * 16384 + 8192);                     \
      GLD_LDS16(gsrc + 49152, ldst + (SS) * 16384 + 12288);                    \
      gsrc += (GSTEP);                                                         \
    }                                                                          \
    i32x8 aF[2], bF[4];                                                        \
    _Pragma("unroll")                                                          \
    for (int rf = 0; rf < 2; ++rf)                                             \
      aF[rf] = *(const i32x8*)(AsP + ((KP & 1) ? aB1[rf] : aB0[rf]) +          \
                               (KP >> 1) * 256);                               \
    _Pragma("unroll")                                                          \
    for (int cf = 0; cf < 4; ++cf)                                             \
      bF[cf] = *(const i32x8*)(BsP + (RS) * 16384 + bB[cf]);                   \
    __builtin_amdgcn_s_setprio(1);                                             \
    _Pragma("unroll")                                                          \
    for (int rf = 0; rf < 2; ++rf)                                             \
      _Pragma("unroll")                                                        \
      for (int cf = 0; cf < 4; ++cf) {                                         \
        if (KP == 0) {                                                         \
          ffrag z = {0.f, 0.f, 0.f, 0.f};                                      \
          acc[rf][cf] = __builtin_amdgcn_mfma_scale_f32_16x16x128_f8f6f4(      \
              aF[rf], bF[cf], z, 0, 0, 0, 0x7F7F7F7F, 0, 0x7F7F7F7F);          \
        } else {                                                               \
          acc[rf][cf] = __builtin_amdgcn_mfma_scale_f32_16x16x128_f8f6f4(      \
              aF[rf], bF[cf], acc[rf][cf], 0, 0, 0, 0x7F7F7F7F, 0,             \
              0x7F7F7F7F);                                                     \
        }                                                                      \
      }                                                                        \
    __builtin_amdgcn_s_setprio(0);                                             \
    if (KP == 3) {                                                             \
      _Pragma("unroll")                                                        \
      for (int rf = 0; rf < 2; ++rf)                                           \
        _Pragma("unroll")                                                      \
        for (int rg = 0; rg < 4; ++rg) {                                       \
          _Pragma("unroll")                                                    \
          for (int cf = 0; cf < 4; ++cf) {                                     \
            float d = fmaf(-2.0f, acc[rf][cf][rg], c2v[cf]);                   \
            unsigned k = (__float_as_uint(d) & 0xFFFFFF00u) |                  \
                         (unsigned)(((CT) << 2) | cf);                         \
            unsigned lo0 = min(b0k[rf][rg], k), hi0 = max(b0k[rf][rg], k);     \
            b0k[rf][rg] = lo0;                                                 \
            unsigned lo1 = min(b1k[rf][rg], hi0), hi1 = max(b1k[rf][rg], hi0); \
            b1k[rf][rg] = lo1;                                                 \
            b2k[rf][rg] = min(b2k[rf][rg], hi1);                               \
          }                                                                    \
        }                                                                      \
    }                                                                          \
    VMW(VMN);                                                                  \
    asm volatile("s_waitcnt lgkmcnt(0)" ::: "memory");                         \
    __builtin_amdgcn_s_barrier();                                              \
  }

  // main loop: 21 x 12 phases (3 cts each); slot/kp pattern period = 12
  for (int c3 = 0; c3 < 21; ++c3) {
    const int ct0 = c3 * 3;
    PH(0, 0, 2, ct0,     1, 128,   4)
    PH(1, 1, 0, ct0,     1, 65152, 4)
    PH(2, 2, 1, ct0,     1, 128,   4)
    PH(3, 0, 2, ct0,     1, 128,   4)
    PH(0, 1, 0, ct0 + 1, 1, 128,   4)
    PH(1, 2, 1, ct0 + 1, 1, 65152, 4)
    PH(2, 0, 2, ct0 + 1, 1, 128,   4)
    PH(3, 1, 0, ct0 + 1, 1, 128,   4)
    PH(0, 2, 1, ct0 + 2, 1, 128,   4)
    PH(1, 0, 2, ct0 + 2, 1, 65152, 4)
    PH(2, 1, 0, ct0 + 2, 1, 128,   4)
    PH(3, 2, 1, ct0 + 2, 1, 128,   4)
  }
  // tail: ct = 63 (phases t=252..255; stages ts=254,255 then drain)
  {
    const int ctT = 63;
    PH(0, 0, 2, ctT, 1, 128, 4)
    PH(1, 1, 0, ctT, 1, 0,   4)
    PH(2, 2, 1, ctT, 0, 0,   0)
    PH(3, 0, 2, ctT, 0, 0,   0)
  }
#undef PH

  // per-row min across 16 l15-lanes; cross-wc merge via LDS (overlay on Bs)
  unsigned* dstar = (unsigned*)&Bs[0][0];   // [2][64]
  unsigned gmin[2][4];
  #pragma unroll
  for (int rf = 0; rf < 2; ++rf)
    #pragma unroll
    for (int rg = 0; rg < 4; ++rg) {
      unsigned g = b0k[rf][rg];
      #pragma unroll
      for (int m = 1; m < 16; m <<= 1)
        g = min(g, (unsigned)__shfl_xor((int)g, m, 64));
      gmin[rf][rg] = g;
      if (l15 == 0) dstar[wc * 64 + wr * 32 + rf * 16 + l4 * 4 + rg] = g;
    }
  __syncthreads();
  #pragma unroll
  for (int rf = 0; rf < 2; ++rf)
    #pragma unroll
    for (int rg = 0; rg < 4; ++rg) {
      int rl = wr * 32 + rf * 16 + l4 * 4 + rg;
      unsigned gg = min(gmin[rf][rg], dstar[(wc ^ 1) * 64 + rl]);
      float ds = __uint_as_float(gg & 0xFFFFFF00u);
      unsigned thr = __float_as_uint(ds + MARGIN);
      int base = (row0 + rl) * 96 + wc * 48 + l15 * 3;
      unsigned kk0 = b0k[rf][rg], kk1 = b1k[rf][rg], kk2 = b2k[rf][rg];
      int c0 = (int)((kk0 >> 2) & 63u) * 128 + wc * 64 + (int)(kk0 & 3u) * 16 + l15;
      int c1 = (int)((kk1 >> 2) & 63u) * 128 + wc * 64 + (int)(kk1 & 3u) * 16 + l15;
      int c2i = (int)((kk2 >> 2) & 63u) * 128 + wc * 64 + (int)(kk2 & 3u) * 16 + l15;
      cand[base + 0] = (kk0 <= thr) ? c0 : -1;
      cand[base + 1] = (kk1 <= thr) ? c1 : -1;
      cand[base + 2] = (kk2 <= thr) ? c2i : -1;
    }
}

// ---- exact fp64 refine over candidate set (one wave per row, 96 slots) -----
__global__ void vq_refine(const float* __restrict__ X, const float* __restrict__ Cb,
                          const int* __restrict__ cand, float* __restrict__ idx_out) {
  int row = (blockIdx.x * blockDim.x + threadIdx.x) >> 6;
  int lane = threadIdx.x & 63;
  if (row >= NTOK) return;
  int cv0 = cand[row * 96 + lane];
  int cv1 = (lane < 32) ? cand[row * 96 + 64 + lane] : -1;
  unsigned long long m0 = __ballot(cv0 >= 0);
  unsigned long long m1 = __ballot(cv1 >= 0);
  if (__popcll(m0) + __popcll(m1) == 1) {
    int idx;
    if (m0) idx = __shfl(cv0, __ffsll(m0) - 1, 64);
    else    idx = __shfl(cv1, __ffsll(m1) - 1, 64);
    if (lane == 0) idx_out[row] = (float)idx;
    return;
  }
  const float4* x4 = (const float4*)(X + (size_t)row * DIM);
  float4 xa = x4[lane * 2], xb = x4[lane * 2 + 1];
  double bestd = 1e300; int besti = 0x7FFFFFFF;
  #pragma unroll
  for (int part = 0; part < 2; ++part) {
    unsigned long long mm = part == 0 ? m0 : m1;
    int cv = part == 0 ? cv0 : cv1;
    while (mm) {
      int src = __ffsll(mm) - 1; mm &= mm - 1;
      int idx = __shfl(cv, src, 64);
      const float4* c4 = (const float4*)(Cb + (size_t)idx * DIM);
      float4 ca = c4[lane * 2], cb = c4[lane * 2 + 1];
      double dt = (double)xa.x*ca.x + (double)xa.y*ca.y + (double)xa.z*ca.z + (double)xa.w*ca.w
                + (double)xb.x*cb.x + (double)xb.y*cb.y + (double)xb.z*cb.z + (double)xb.w*cb.w;
      double cc = (double)ca.x*ca.x + (double)ca.y*ca.y + (double)ca.z*ca.z + (double)ca.w*ca.w
                + (double)cb.x*cb.x + (double)cb.y*cb.y + (double)cb.z*cb.z + (double)cb.w*cb.w;
      double sdist = cc - 2.0 * dt;           // x2 omitted: per-row constant
      #pragma unroll
      for (int off = 32; off; off >>= 1) sdist += __shfl_down(sdist, off, 64);
      if (lane == 0 && (sdist < bestd || (sdist == bestd && idx < besti))) { bestd = sdist; besti = idx; }
    }
  }
  if (lane == 0) idx_out[row] = (float)besti;
}

// ---- final: quantized = inputs (runs LAST; overwrites scratch) -------------
__global__ void vq_copy(const float* __restrict__ in, float* __restrict__ out, int n4) {
  int i = blockIdx.x * blockDim.x + threadIdx.x;
  int st = gridDim.x * blockDim.x;
  const float4* s = (const float4*)in;
  float4* d = (float4*)out;
  for (; i < n4; i += st) d[i] = s[i];
}

extern "C" void kernel_launch(void* const* d_in, const int* in_sizes, int n_in,
                              void* d_out, int out_size, void* d_ws, size_t ws_size,
                              hipStream_t stream) {
  const float* X  = (const float*)d_in[0];
  const float* Cb = (const float*)d_in[1];
  float* out = (float*)d_out;

  unsigned char* Xq   = (unsigned char*)out;                  // [N][512] fp8
  unsigned char* Cq   = (unsigned char*)(out + 4194304);      // [K][512] fp8
  int*           cand = (int*)(out + 5242880);                // [N][96]
  float*         c2   = (float*)d_ws;                         // [K]
  float*         idx_out = out + (size_t)NTOK * DIM;

  vq_prep8<<<KCODES / 4, 256, 0, stream>>>(Cb, Cq, c2, KCODES);
  vq_prep8<<<NTOK / 4, 256, 0, stream>>>(X, Xq, nullptr, NTOK);
  vq_main<<<NTOK / 64, 256, 0, stream>>>(Xq, Cq, c2, cand);
  vq_refine<<<NTOK / 4, 256, 0, stream>>>(X, Cb, cand, idx_out);
  vq_copy<<<2048, 256, 0, stream>>>(X, out, NTOK * DIM / 4);
}

// Round 15
// 246.520 us; speedup vs baseline: 1.3067x; 1.3067x over previous
//
#include <hip/hip_runtime.h>
#include <hip/hip_bf16.h>

// VQ argmin via MX-scaled fp8 (e4m3, scale=1.0) K=128 MFMA filter + exact
// fp64 refine. Round 15: REVERT to round-13 (proven 193us vq_main).
// Round-14's contiguous-32B layout put every b128 on 4 of 8 bank groups
// (4-way conflict, +600 cyc/phase); the 16B-unit 3-bit XOR layout is
// load-bearing and its repack movs are off the critical path.
// Scratch carved from d_out[0:N*D) (float offsets):
//   Xq  fp8[N][512]   @ 0        (16 MiB)
//   Cq  fp8[K][512]   @ 4194304  ( 4 MiB)
//   cand int[N][96]   @ 5242880  (12 MiB)
// c2 f32[K] in d_ws.

constexpr int NTOK = 32768, DIM = 512, KCODES = 8192;
constexpr float MARGIN = 20.0f;

using ffrag = __attribute__((ext_vector_type(4))) float;   // 4 f32 acc
using i32x4 = __attribute__((ext_vector_type(4))) int;
using i32x8 = __attribute__((ext_vector_type(8))) int;

#define GLD_LDS16(g, l)                                                        \
  __builtin_amdgcn_global_load_lds(                                            \
      (const __attribute__((address_space(1))) void*)(g),                      \
      (__attribute__((address_space(3))) void*)(l), 16, 0, 0)
#define VMW(N) asm volatile("s_waitcnt vmcnt(" #N ")" ::: "memory")

// ---- f32 -> fp8 e4m3fn, explicit RNE ---------------------------------------
__device__ __forceinline__ unsigned char f2e4m3(float x) {
  unsigned u = __float_as_uint(x);
  unsigned s = (u >> 24) & 0x80u;
  float ax = fabsf(x);
  if (ax < 0.015625f) {
    int q = (int)rintf(ax * 512.0f);
    return (unsigned char)(s | (unsigned)q);
  }
  int e = (int)((u >> 23) & 0xFF) - 127;
  float m = __uint_as_float((u & 0x7FFFFFu) | 0x3F800000u);
  int r = (int)rintf(m * 8.0f);
  if (r == 16) { r = 8; ++e; }
  if (e > 8) { e = 8; r = 15; }
  return (unsigned char)(s | ((unsigned)(e + 7) << 3) | (unsigned)(r - 8));
}

// ---- convert fp32 rows -> fp8, optional sum-of-squares ---------------------
__global__ void vq_prep8(const float* __restrict__ src, unsigned char* __restrict__ dst,
                         float* __restrict__ sq, int rows) {
  int w = (blockIdx.x * blockDim.x + threadIdx.x) >> 6;
  int lane = threadIdx.x & 63;
  if (w >= rows) return;
  const float4* r4 = (const float4*)(src + (size_t)w * DIM);
  float4 a = r4[lane * 2], b = r4[lane * 2 + 1];
  union { unsigned char c[8]; uint2 v; } o;
  o.c[0]=f2e4m3(a.x); o.c[1]=f2e4m3(a.y); o.c[2]=f2e4m3(a.z); o.c[3]=f2e4m3(a.w);
  o.c[4]=f2e4m3(b.x); o.c[5]=f2e4m3(b.y); o.c[6]=f2e4m3(b.z); o.c[7]=f2e4m3(b.w);
  *(uint2*)(dst + (size_t)w * DIM + lane * 8) = o.v;
  if (sq != nullptr) {
    float s = a.x*a.x + a.y*a.y + a.z*a.z + a.w*a.w
            + b.x*b.x + b.y*b.y + b.z*b.z + b.w*b.w;
    #pragma unroll
    for (int off = 32; off; off >>= 1) s += __shfl_down(s, off, 64);
    if (lane == 0) sq[w] = s;
  }
}

// ---- fused MX-fp8 K=128 MFMA distance + best-3 + candidate emission --------
// Block: 256 thr (4 waves: wr,wc in {0,1}), 64 rows x FULL 8192 codes.
// As [64 rows][32 units], unit stored at u^(row&7). Slab ring-3 of
// [128 cols][8 units], unit stored at u^(col&7). Phase protocol:
// {c2(kp2) | stage(t+2)} -> read frags(t) -> MFMA -> epi -> VMW(4)+lgkm(0)
// -> barrier. 12-phase unroll makes slots/kp compile-time.
__launch_bounds__(256, 2)
__global__ void vq_main(const unsigned char* __restrict__ Xq,
                        const unsigned char* __restrict__ Cq,
                        const float* __restrict__ c2g, int* __restrict__ cand) {
  __shared__ __align__(16) unsigned char As[64 * 512];     // 32 KiB
  __shared__ __align__(16) unsigned char Bs[3][16384];     // 48 KiB ring-3
  const int tid = threadIdx.x, lane = tid & 63;
  const int wid = tid >> 6, wr = wid >> 1, wc = wid & 1;
  const int row0 = blockIdx.x * 64;
  const int l15 = lane & 15, l4 = lane >> 4;

  // ---------- prologue staging (slabs ts=0,1 into slots 0,1) ----------
  #pragma unroll
  for (int it = 0; it < 8; ++it) {        // As: 16B-unit swizzled source
    int p = it * 256 + tid, rA = p >> 5, u = p & 31;
    GLD_LDS16(Xq + (size_t)(row0 + rA) * DIM + ((u ^ (rA & 7)) << 4),
              &As[0] + p * 16);
  }
  #pragma unroll
  for (int t0 = 0; t0 < 2; ++t0) {
    #pragma unroll
    for (int i = 0; i < 4; ++i) {
      int p = i * 256 + tid, c = p >> 3, u = p & 7;
      GLD_LDS16(Cq + (size_t)c * DIM + t0 * 128 + ((u ^ (c & 7)) << 4),
                &Bs[t0][0] + p * 16);
    }
  }
  VMW(4);                                  // As + slab0 landed (slab1 flying)
  __builtin_amdgcn_s_barrier();

  // ---------- hoisted per-thread address state ----------
  int aLo[2], aHi[2];
  #pragma unroll
  for (int rf = 0; rf < 2; ++rf) {
    int rA = wr * 32 + rf * 16 + l15, sw = rA & 7;
    aLo[rf] = rA * 512 + (((2 * l4) ^ sw) << 4);
    aHi[rf] = rA * 512 + (((2 * l4 + 1) ^ sw) << 4);
  }
  int bLo[4], bHi[4];
  #pragma unroll
  for (int cf = 0; cf < 4; ++cf) {
    int rB = wc * 64 + cf * 16 + l15, sw = rB & 7;
    bLo[cf] = rB * 128 + (((2 * l4) ^ sw) << 4);
    bHi[cf] = rB * 128 + (((2 * l4 + 1) ^ sw) << 4);
  }
  const int cS = tid >> 3, uS = tid & 7;
  const unsigned char* gsrc = Cq + cS * 512 + ((uS ^ (cS & 7)) << 4) + 256; // ts=2
  const float* c2p = c2g + wc * 64 + l15;
  unsigned char* ldst = &Bs[0][0] + tid * 16;
  const unsigned char* AsP = &As[0];
  const unsigned char* BsP = &Bs[0][0];

  unsigned b0k[2][4], b1k[2][4], b2k[2][4];
  #pragma unroll
  for (int rf = 0; rf < 2; ++rf)
    #pragma unroll
    for (int rg = 0; rg < 4; ++rg) {
      b0k[rf][rg] = 0xFFFFFFFFu; b1k[rf][rg] = 0xFFFFFFFFu; b2k[rf][rg] = 0xFFFFFFFFu;
    }
  ffrag acc[2][4];
  float c2v[4];

// One phase. KP/RS/SS/GSTEP/VMN are literals; CT is a runtime int.
#define PH(KP, RS, SS, CT, STG, GSTEP, VMN)                                    \
  {                                                                            \
    if (KP == 2) {                                                             \
      c2v[0] = c2p[0];  c2v[1] = c2p[16];                                      \
      c2v[2] = c2p[32]; c2v[3] = c2p[48];                                      \
      c2p += 128;                                                              \
    }                                                                          \
    if (STG) {                                                                 \
      GLD_LDS16(gsrc,         ldst + (SS) * 16384 + 0);                        \
      GLD_LDS16(gsrc + 16384, ldst + (SS) * 16384 + 4096);                     \
      GLD_LDS16(gsrc + 32768, ldst + (SS) * 16384 + 8192);                     \
      GLD_LDS16(gsrc + 49152, ldst + (SS) * 16384 + 12288);                    \
      gsrc += (GSTEP);                                                         \
    }                                                                          \
    i32x8 aF[2], bF[4];                                                        \
    _Pragma("unroll")                                                          \
    for (int rf = 0; rf < 2; ++rf) {                                           \
      i32x4 lo = *(const i32x4*)(AsP + aLo[rf] + (KP) * 128);                  \
      i32x4 hi = *(const i32x4*)(AsP + aHi[rf] + (KP) * 128);                  \
      aF[rf] = __builtin_shufflevector(lo, hi, 0, 1, 2, 3, 4, 5, 6, 7);        \
    }                                                                          \
    _Pragma("unroll")                                                          \
    for (int cf = 0; cf < 4; ++cf) {                                           \
      i32x4 lo = *(const i32x4*)(BsP + (RS) * 16384 + bLo[cf]);                \
      i32x4 hi = *(const i32x4*)(BsP + (RS) * 16384 + bHi[cf]);                \
      bF[cf] = __builtin_shufflevector(lo, hi, 0, 1, 2, 3, 4, 5, 6, 7);        \
    }                                                                          \
    __builtin_amdgcn_s_setprio(1);                                             \
    _Pragma("unroll")                                                          \
    for (int rf = 0; rf < 2; ++rf)                                             \
      _Pragma("unroll")                                                        \
      for (int cf = 0; cf < 4; ++cf) {                                         \
        if (KP == 0) {                                                         \
          ffrag z = {0.f, 0.f, 0.f, 0.f};                                      \
          acc[rf][cf] = __builtin_amdgcn_mfma_scale_f32_16x16x128_f8f6f4(      \
              aF[rf], bF[cf], z, 0, 0, 0, 0x7F7F7F7F, 0, 0x7F7F7F7F);          \
        } else {                                                               \
          acc[rf][cf] = __builtin_amdgcn_mfma_scale_f32_16x16x128_f8f6f4(      \
              aF[rf], bF[cf], acc[rf][cf], 0, 0, 0, 0x7F7F7F7F, 0,             \
              0x7F7F7F7F);                                                     \
        }                                                                      \
      }                                                                        \
    __builtin_amdgcn_s_setprio(0);                                             \
    if (KP == 3) {                                                             \
      _Pragma("unroll")                                                        \
      for (int rf = 0; rf < 2; ++rf)                                           \
        _Pragma("unroll")                                                      \
        for (int rg = 0; rg < 4; ++rg) {                                       \
          _Pragma("unroll")                                                    \
          for (int cf = 0; cf < 4; ++cf) {                                     \
            float d = fmaf(-2.0f, acc[rf][cf][rg], c2v[cf] + 2048.0f);         \
            unsigned k = (__float_as_uint(d) & 0xFFFFFF00u) |                  \
                         (unsigned)(((CT) << 2) | cf);                         \
            unsigned lo0 = min(b0k[rf][rg], k), hi0 = max(b0k[rf][rg], k);     \
            b0k[rf][rg] = lo0;                                                 \
            unsigned lo1 = min(b1k[rf][rg], hi0), hi1 = max(b1k[rf][rg], hi0); \
            b1k[rf][rg] = lo1;                                                 \
            b2k[rf][rg] = min(b2k[rf][rg], hi1);                               \
          }                                                                    \
        }                                                                      \
    }                                                                          \
    VMW(VMN);                                                                  \
    asm volatile("s_waitcnt lgkmcnt(0)" ::: "memory");                         \
    __builtin_amdgcn_s_barrier();                                              \
  }

  // main loop: 21 x 12 phases (3 cts each); slot/kp pattern period = 12
  for (int c3 = 0; c3 < 21; ++c3) {
    const int ct0 = c3 * 3;
    PH(0, 0, 2, ct0,     1, 128,   4)
    PH(1, 1, 0, ct0,     1, 65152, 4)
    PH(2, 2, 1, ct0,     1, 128,   4)
    PH(3, 0, 2, ct0,     1, 128,   4)
    PH(0, 1, 0, ct0 + 1, 1, 128,   4)
    PH(1, 2, 1, ct0 + 1, 1, 65152, 4)
    PH(2, 0, 2, ct0 + 1, 1, 128,   4)
    PH(3, 1, 0, ct0 + 1, 1, 128,   4)
    PH(0, 2, 1, ct0 + 2, 1, 128,   4)
    PH(1, 0, 2, ct0 + 2, 1, 65152, 4)
    PH(2, 1, 0, ct0 + 2, 1, 128,   4)
    PH(3, 2, 1, ct0 + 2, 1, 128,   4)
  }
  // tail: ct = 63 (phases t=252..255; stages ts=254,255 then drain)
  {
    const int ctT = 63;
    PH(0, 0, 2, ctT, 1, 128, 4)
    PH(1, 1, 0, ctT, 1, 0,   4)
    PH(2, 2, 1, ctT, 0, 0,   0)
    PH(3, 0, 2, ctT, 0, 0,   0)
  }
#undef PH

  // per-row min across 16 l15-lanes; cross-wc merge via LDS (overlay on Bs)
  unsigned* dstar = (unsigned*)&Bs[0][0];   // [2][64]
  unsigned gmin[2][4];
  #pragma unroll
  for (int rf = 0; rf < 2; ++rf)
    #pragma unroll
    for (int rg = 0; rg < 4; ++rg) {
      unsigned g = b0k[rf][rg];
      #pragma unroll
      for (int m = 1; m < 16; m <<= 1)
        g = min(g, (unsigned)__shfl_xor((int)g, m, 64));
      gmin[rf][rg] = g;
      if (l15 == 0) dstar[wc * 64 + wr * 32 + rf * 16 + l4 * 4 + rg] = g;
    }
  __syncthreads();
  #pragma unroll
  for (int rf = 0; rf < 2; ++rf)
    #pragma unroll
    for (int rg = 0; rg < 4; ++rg) {
      int rl = wr * 32 + rf * 16 + l4 * 4 + rg;
      unsigned gg = min(gmin[rf][rg], dstar[(wc ^ 1) * 64 + rl]);
      float ds = __uint_as_float(gg & 0xFFFFFF00u);
      unsigned thr = __float_as_uint(ds + MARGIN);
      int base = (row0 + rl) * 96 + wc * 48 + l15 * 3;
      unsigned kk0 = b0k[rf][rg], kk1 = b1k[rf][rg], kk2 = b2k[rf][rg];
      int c0 = (int)((kk0 >> 2) & 63u) * 128 + wc * 64 + (int)(kk0 & 3u) * 16 + l15;
      int c1 = (int)((kk1 >> 2) & 63u) * 128 + wc * 64 + (int)(kk1 & 3u) * 16 + l15;
      int c2i = (int)((kk2 >> 2) & 63u) * 128 + wc * 64 + (int)(kk2 & 3u) * 16 + l15;
      cand[base + 0] = (kk0 <= thr) ? c0 : -1;
      cand[base + 1] = (kk1 <= thr) ? c1 : -1;
      cand[base + 2] = (kk2 <= thr) ? c2i : -1;
    }
}

// ---- exact fp64 refine over candidate set (one wave per row, 96 slots) -----
__global__ void vq_refine(const float* __restrict__ X, const float* __restrict__ Cb,
                          const int* __restrict__ cand, float* __restrict__ idx_out) {
  int row = (blockIdx.x * blockDim.x + threadIdx.x) >> 6;
  int lane = threadIdx.x & 63;
  if (row >= NTOK) return;
  int cv0 = cand[row * 96 + lane];
  int cv1 = (lane < 32) ? cand[row * 96 + 64 + lane] : -1;
  unsigned long long m0 = __ballot(cv0 >= 0);
  unsigned long long m1 = __ballot(cv1 >= 0);
  if (__popcll(m0) + __popcll(m1) == 1) {
    int idx;
    if (m0) idx = __shfl(cv0, __ffsll(m0) - 1, 64);
    else    idx = __shfl(cv1, __ffsll(m1) - 1, 64);
    if (lane == 0) idx_out[row] = (float)idx;
    return;
  }
  const float4* x4 = (const float4*)(X + (size_t)row * DIM);
  float4 xa = x4[lane * 2], xb = x4[lane * 2 + 1];
  double bestd = 1e300; int besti = 0x7FFFFFFF;
  #pragma unroll
  for (int part = 0; part < 2; ++part) {
    unsigned long long mm = part == 0 ? m0 : m1;
    int cv = part == 0 ? cv0 : cv1;
    while (mm) {
      int src = __ffsll(mm) - 1; mm &= mm - 1;
      int idx = __shfl(cv, src, 64);
      const float4* c4 = (const float4*)(Cb + (size_t)idx * DIM);
      float4 ca = c4[lane * 2], cb = c4[lane * 2 + 1];
      double dt = (double)xa.x*ca.x + (double)xa.y*ca.y + (double)xa.z*ca.z + (double)xa.w*ca.w
                + (double)xb.x*cb.x + (double)xb.y*cb.y + (double)xb.z*cb.z + (double)xb.w*cb.w;
      double cc = (double)ca.x*ca.x + (double)ca.y*ca.y + (double)ca.z*ca.z + (double)ca.w*ca.w
                + (double)cb.x*cb.x + (double)cb.y*cb.y + (double)cb.z*cb.z + (double)cb.w*cb.w;
      double sdist = cc - 2.0 * dt;           // x2 omitted: per-row constant
      #pragma unroll
      for (int off = 32; off; off >>= 1) sdist += __shfl_down(sdist, off, 64);
      if (lane == 0 && (sdist < bestd || (sdist == bestd && idx < besti))) { bestd = sdist; besti = idx; }
    }
  }
  if (lane == 0) idx_out[row] = (float)besti;
}

// ---- final: quantized = inputs (runs LAST; overwrites scratch) -------------
__global__ void vq_copy(const float* __restrict__ in, float* __restrict__ out, int n4) {
  int i = blockIdx.x * blockDim.x + threadIdx.x;
  int st = gridDim.x * blockDim.x;
  const float4* s = (const float4*)in;
  float4* d = (float4*)out;
  for (; i < n4; i += st) d[i] = s[i];
}

extern "C" void kernel_launch(void* const* d_in, const int* in_sizes, int n_in,
                              void* d_out, int out_size, void* d_ws, size_t ws_size,
                              hipStream_t stream) {
  const float* X  = (const float*)d_in[0];
  const float* Cb = (const float*)d_in[1];
  float* out = (float*)d_out;

  unsigned char* Xq   = (unsigned char*)out;                  // [N][512] fp8
  unsigned char* Cq   = (unsigned char*)(out + 4194304);      // [K][512] fp8
  int*           cand = (int*)(out + 5242880);                // [N][96]
  float*         c2   = (float*)d_ws;                         // [K]
  float*         idx_out = out + (size_t)NTOK * DIM;

  vq_prep8<<<KCODES / 4, 256, 0, stream>>>(Cb, Cq, c2, KCODES);
  vq_prep8<<<NTOK / 4, 256, 0, stream>>>(X, Xq, nullptr, NTOK);
  vq_main<<<NTOK / 64, 256, 0, stream>>>(Xq, Cq, c2, cand);
  vq_refine<<<NTOK / 4, 256, 0, stream>>>(X, Cb, cand, idx_out);
  vq_copy<<<2048, 256, 0, stream>>>(X, out, NTOK * DIM / 4);
}

// Round 16
// 236.776 us; speedup vs baseline: 1.3605x; 1.0412x over previous
//
#include <hip/hip_runtime.h>
#include <hip/hip_bf16.h>

// VQ argmin via MX-scaled fp8 (e4m3, scale=1.0) K=128 MFMA filter + exact
// fp64 refine. Round 16: vq_main untouched (r13/r15 proven, 192us). Helper
// fusion: if ws_size >= 33.6MB, move ALL scratch (Xq/Cq/cand/c2) to d_ws,
// fuse copy+prep8(X) into one kernel (read X once), drop vq_copy -> saves
// 64MB HBM read + one launch. Guarded fallback to the r15 path otherwise.

constexpr int NTOK = 32768, DIM = 512, KCODES = 8192;
constexpr float MARGIN = 20.0f;

using ffrag = __attribute__((ext_vector_type(4))) float;   // 4 f32 acc
using i32x4 = __attribute__((ext_vector_type(4))) int;
using i32x8 = __attribute__((ext_vector_type(8))) int;

#define GLD_LDS16(g, l)                                                        \
  __builtin_amdgcn_global_load_lds(                                            \
      (const __attribute__((address_space(1))) void*)(g),                      \
      (__attribute__((address_space(3))) void*)(l), 16, 0, 0)
#define VMW(N) asm volatile("s_waitcnt vmcnt(" #N ")" ::: "memory")

// ---- f32 -> fp8 e4m3fn, explicit RNE ---------------------------------------
__device__ __forceinline__ unsigned char f2e4m3(float x) {
  unsigned u = __float_as_uint(x);
  unsigned s = (u >> 24) & 0x80u;
  float ax = fabsf(x);
  if (ax < 0.015625f) {
    int q = (int)rintf(ax * 512.0f);
    return (unsigned char)(s | (unsigned)q);
  }
  int e = (int)((u >> 23) & 0xFF) - 127;
  float m = __uint_as_float((u & 0x7FFFFFu) | 0x3F800000u);
  int r = (int)rintf(m * 8.0f);
  if (r == 16) { r = 8; ++e; }
  if (e > 8) { e = 8; r = 15; }
  return (unsigned char)(s | ((unsigned)(e + 7) << 3) | (unsigned)(r - 8));
}

// ---- convert fp32 rows -> fp8, optional sum-of-squares ---------------------
__global__ void vq_prep8(const float* __restrict__ src, unsigned char* __restrict__ dst,
                         float* __restrict__ sq, int rows) {
  int w = (blockIdx.x * blockDim.x + threadIdx.x) >> 6;
  int lane = threadIdx.x & 63;
  if (w >= rows) return;
  const float4* r4 = (const float4*)(src + (size_t)w * DIM);
  float4 a = r4[lane * 2], b = r4[lane * 2 + 1];
  union { unsigned char c[8]; uint2 v; } o;
  o.c[0]=f2e4m3(a.x); o.c[1]=f2e4m3(a.y); o.c[2]=f2e4m3(a.z); o.c[3]=f2e4m3(a.w);
  o.c[4]=f2e4m3(b.x); o.c[5]=f2e4m3(b.y); o.c[6]=f2e4m3(b.z); o.c[7]=f2e4m3(b.w);
  *(uint2*)(dst + (size_t)w * DIM + lane * 8) = o.v;
  if (sq != nullptr) {
    float s = a.x*a.x + a.y*a.y + a.z*a.z + a.w*a.w
            + b.x*b.x + b.y*b.y + b.z*b.z + b.w*b.w;
    #pragma unroll
    for (int off = 32; off; off >>= 1) s += __shfl_down(s, off, 64);
    if (lane == 0) sq[w] = s;
  }
}

// ---- fused: out = src (copy) AND dst = fp8(src) ----------------------------
__global__ void vq_copyprep8(const float* __restrict__ src, float* __restrict__ outc,
                             unsigned char* __restrict__ dst, int rows) {
  int w = (blockIdx.x * blockDim.x + threadIdx.x) >> 6;
  int lane = threadIdx.x & 63;
  if (w >= rows) return;
  const float4* r4 = (const float4*)(src + (size_t)w * DIM);
  float4 a = r4[lane * 2], b = r4[lane * 2 + 1];
  float4* o4 = (float4*)(outc + (size_t)w * DIM);
  o4[lane * 2] = a; o4[lane * 2 + 1] = b;
  union { unsigned char c[8]; uint2 v; } o;
  o.c[0]=f2e4m3(a.x); o.c[1]=f2e4m3(a.y); o.c[2]=f2e4m3(a.z); o.c[3]=f2e4m3(a.w);
  o.c[4]=f2e4m3(b.x); o.c[5]=f2e4m3(b.y); o.c[6]=f2e4m3(b.z); o.c[7]=f2e4m3(b.w);
  *(uint2*)(dst + (size_t)w * DIM + lane * 8) = o.v;
}

// ---- fused MX-fp8 K=128 MFMA distance + best-3 + candidate emission --------
// (byte-identical to round 13/15 — proven 192us)
__launch_bounds__(256, 2)
__global__ void vq_main(const unsigned char* __restrict__ Xq,
                        const unsigned char* __restrict__ Cq,
                        const float* __restrict__ c2g, int* __restrict__ cand) {
  __shared__ __align__(16) unsigned char As[64 * 512];     // 32 KiB
  __shared__ __align__(16) unsigned char Bs[3][16384];     // 48 KiB ring-3
  const int tid = threadIdx.x, lane = tid & 63;
  const int wid = tid >> 6, wr = wid >> 1, wc = wid & 1;
  const int row0 = blockIdx.x * 64;
  const int l15 = lane & 15, l4 = lane >> 4;

  #pragma unroll
  for (int it = 0; it < 8; ++it) {        // As: 16B-unit swizzled source
    int p = it * 256 + tid, rA = p >> 5, u = p & 31;
    GLD_LDS16(Xq + (size_t)(row0 + rA) * DIM + ((u ^ (rA & 7)) << 4),
              &As[0] + p * 16);
  }
  #pragma unroll
  for (int t0 = 0; t0 < 2; ++t0) {
    #pragma unroll
    for (int i = 0; i < 4; ++i) {
      int p = i * 256 + tid, c = p >> 3, u = p & 7;
      GLD_LDS16(Cq + (size_t)c * DIM + t0 * 128 + ((u ^ (c & 7)) << 4),
                &Bs[t0][0] + p * 16);
    }
  }
  VMW(4);
  __builtin_amdgcn_s_barrier();

  int aLo[2], aHi[2];
  #pragma unroll
  for (int rf = 0; rf < 2; ++rf) {
    int rA = wr * 32 + rf * 16 + l15, sw = rA & 7;
    aLo[rf] = rA * 512 + (((2 * l4) ^ sw) << 4);
    aHi[rf] = rA * 512 + (((2 * l4 + 1) ^ sw) << 4);
  }
  int bLo[4], bHi[4];
  #pragma unroll
  for (int cf = 0; cf < 4; ++cf) {
    int rB = wc * 64 + cf * 16 + l15, sw = rB & 7;
    bLo[cf] = rB * 128 + (((2 * l4) ^ sw) << 4);
    bHi[cf] = rB * 128 + (((2 * l4 + 1) ^ sw) << 4);
  }
  const int cS = tid >> 3, uS = tid & 7;
  const unsigned char* gsrc = Cq + cS * 512 + ((uS ^ (cS & 7)) << 4) + 256; // ts=2
  const float* c2p = c2g + wc * 64 + l15;
  unsigned char* ldst = &Bs[0][0] + tid * 16;
  const unsigned char* AsP = &As[0];
  const unsigned char* BsP = &Bs[0][0];

  unsigned b0k[2][4], b1k[2][4], b2k[2][4];
  #pragma unroll
  for (int rf = 0; rf < 2; ++rf)
    #pragma unroll
    for (int rg = 0; rg < 4; ++rg) {
      b0k[rf][rg] = 0xFFFFFFFFu; b1k[rf][rg] = 0xFFFFFFFFu; b2k[rf][rg] = 0xFFFFFFFFu;
    }
  ffrag acc[2][4];
  float c2v[4];

#define PH(KP, RS, SS, CT, STG, GSTEP, VMN)                                    \
  {                                                                            \
    if (KP == 2) {                                                             \
      c2v[0] = c2p[0];  c2v[1] = c2p[16];                                      \
      c2v[2] = c2p[32]; c2v[3] = c2p[48];                                      \
      c2p += 128;                                                              \
    }                                                                          \
    if (STG) {                                                                 \
      GLD_LDS16(gsrc,         ldst + (SS) * 16384 + 0);                        \
      GLD_LDS16(gsrc + 16384, ldst + (SS) * 16384 + 4096);                     \
      GLD_LDS16(gsrc + 32768, ldst + (SS) * 16384 + 8192);                     \
      GLD_LDS16(gsrc + 49152, ldst + (SS) * 16384 + 12288);                    \
      gsrc += (GSTEP);                                                         \
    }                                                                          \
    i32x8 aF[2], bF[4];                                                        \
    _Pragma("unroll")                                                          \
    for (int rf = 0; rf < 2; ++rf) {                                           \
      i32x4 lo = *(const i32x4*)(AsP + aLo[rf] + (KP) * 128);                  \
      i32x4 hi = *(const i32x4*)(AsP + aHi[rf] + (KP) * 128);                  \
      aF[rf] = __builtin_shufflevector(lo, hi, 0, 1, 2, 3, 4, 5, 6, 7);        \
    }                                                                          \
    _Pragma("unroll")                                                          \
    for (int cf = 0; cf < 4; ++cf) {                                           \
      i32x4 lo = *(const i32x4*)(BsP + (RS) * 16384 + bLo[cf]);                \
      i32x4 hi = *(const i32x4*)(BsP + (RS) * 16384 + bHi[cf]);                \
      bF[cf] = __builtin_shufflevector(lo, hi, 0, 1, 2, 3, 4, 5, 6, 7);        \
    }                                                                          \
    __builtin_amdgcn_s_setprio(1);                                             \
    _Pragma("unroll")                                                          \
    for (int rf = 0; rf < 2; ++rf)                                             \
      _Pragma("unroll")                                                        \
      for (int cf = 0; cf < 4; ++cf) {                                         \
        if (KP == 0) {                                                         \
          ffrag z = {0.f, 0.f, 0.f, 0.f};                                      \
          acc[rf][cf] = __builtin_amdgcn_mfma_scale_f32_16x16x128_f8f6f4(      \
              aF[rf], bF[cf], z, 0, 0, 0, 0x7F7F7F7F, 0, 0x7F7F7F7F);          \
        } else {                                                               \
          acc[rf][cf] = __builtin_amdgcn_mfma_scale_f32_16x16x128_f8f6f4(      \
              aF[rf], bF[cf], acc[rf][cf], 0, 0, 0, 0x7F7F7F7F, 0,             \
              0x7F7F7F7F);                                                     \
        }                                                                      \
      }                                                                        \
    __builtin_amdgcn_s_setprio(0);                                             \
    if (KP == 3) {                                                             \
      _Pragma("unroll")                                                        \
      for (int rf = 0; rf < 2; ++rf)                                           \
        _Pragma("unroll")                                                      \
        for (int rg = 0; rg < 4; ++rg) {                                       \
          _Pragma("unroll")                                                    \
          for (int cf = 0; cf < 4; ++cf) {                                     \
            float d = fmaf(-2.0f, acc[rf][cf][rg], c2v[cf] + 2048.0f);         \
            unsigned k = (__float_as_uint(d) & 0xFFFFFF00u) |                  \
                         (unsigned)(((CT) << 2) | cf);                         \
            unsigned lo0 = min(b0k[rf][rg], k), hi0 = max(b0k[rf][rg], k);     \
            b0k[rf][rg] = lo0;                                                 \
            unsigned lo1 = min(b1k[rf][rg], hi0), hi1 = max(b1k[rf][rg], hi0); \
            b1k[rf][rg] = lo1;                                                 \
            b2k[rf][rg] = min(b2k[rf][rg], hi1);                               \
          }                                                                    \
        }                                                                      \
    }                                                                          \
    VMW(VMN);                                                                  \
    asm volatile("s_waitcnt lgkmcnt(0)" ::: "memory");                         \
    __builtin_amdgcn_s_barrier();                                              \
  }

  for (int c3 = 0; c3 < 21; ++c3) {
    const int ct0 = c3 * 3;
    PH(0, 0, 2, ct0,     1, 128,   4)
    PH(1, 1, 0, ct0,     1, 65152, 4)
    PH(2, 2, 1, ct0,     1, 128,   4)
    PH(3, 0, 2, ct0,     1, 128,   4)
    PH(0, 1, 0, ct0 + 1, 1, 128,   4)
    PH(1, 2, 1, ct0 + 1, 1, 65152, 4)
    PH(2, 0, 2, ct0 + 1, 1, 128,   4)
    PH(3, 1, 0, ct0 + 1, 1, 128,   4)
    PH(0, 2, 1, ct0 + 2, 1, 128,   4)
    PH(1, 0, 2, ct0 + 2, 1, 65152, 4)
    PH(2, 1, 0, ct0 + 2, 1, 128,   4)
    PH(3, 2, 1, ct0 + 2, 1, 128,   4)
  }
  {
    const int ctT = 63;
    PH(0, 0, 2, ctT, 1, 128, 4)
    PH(1, 1, 0, ctT, 1, 0,   4)
    PH(2, 2, 1, ctT, 0, 0,   0)
    PH(3, 0, 2, ctT, 0, 0,   0)
  }
#undef PH

  unsigned* dstar = (unsigned*)&Bs[0][0];   // [2][64]
  unsigned gmin[2][4];
  #pragma unroll
  for (int rf = 0; rf < 2; ++rf)
    #pragma unroll
    for (int rg = 0; rg < 4; ++rg) {
      unsigned g = b0k[rf][rg];
      #pragma unroll
      for (int m = 1; m < 16; m <<= 1)
        g = min(g, (unsigned)__shfl_xor((int)g, m, 64));
      gmin[rf][rg] = g;
      if (l15 == 0) dstar[wc * 64 + wr * 32 + rf * 16 + l4 * 4 + rg] = g;
    }
  __syncthreads();
  #pragma unroll
  for (int rf = 0; rf < 2; ++rf)
    #pragma unroll
    for (int rg = 0; rg < 4; ++rg) {
      int rl = wr * 32 + rf * 16 + l4 * 4 + rg;
      unsigned gg = min(gmin[rf][rg], dstar[(wc ^ 1) * 64 + rl]);
      float ds = __uint_as_float(gg & 0xFFFFFF00u);
      unsigned thr = __float_as_uint(ds + MARGIN);
      int base = (row0 + rl) * 96 + wc * 48 + l15 * 3;
      unsigned kk0 = b0k[rf][rg], kk1 = b1k[rf][rg], kk2 = b2k[rf][rg];
      int c0 = (int)((kk0 >> 2) & 63u) * 128 + wc * 64 + (int)(kk0 & 3u) * 16 + l15;
      int c1 = (int)((kk1 >> 2) & 63u) * 128 + wc * 64 + (int)(kk1 & 3u) * 16 + l15;
      int c2i = (int)((kk2 >> 2) & 63u) * 128 + wc * 64 + (int)(kk2 & 3u) * 16 + l15;
      cand[base + 0] = (kk0 <= thr) ? c0 : -1;
      cand[base + 1] = (kk1 <= thr) ? c1 : -1;
      cand[base + 2] = (kk2 <= thr) ? c2i : -1;
    }
}

// ---- exact fp64 refine over candidate set (one wave per row, 96 slots) -----
__global__ void vq_refine(const float* __restrict__ X, const float* __restrict__ Cb,
                          const int* __restrict__ cand, float* __restrict__ idx_out) {
  int row = (blockIdx.x * blockDim.x + threadIdx.x) >> 6;
  int lane = threadIdx.x & 63;
  if (row >= NTOK) return;
  int cv0 = cand[row * 96 + lane];
  int cv1 = (lane < 32) ? cand[row * 96 + 64 + lane] : -1;
  unsigned long long m0 = __ballot(cv0 >= 0);
  unsigned long long m1 = __ballot(cv1 >= 0);
  if (__popcll(m0) + __popcll(m1) == 1) {
    int idx;
    if (m0) idx = __shfl(cv0, __ffsll(m0) - 1, 64);
    else    idx = __shfl(cv1, __ffsll(m1) - 1, 64);
    if (lane == 0) idx_out[row] = (float)idx;
    return;
  }
  const float4* x4 = (const float4*)(X + (size_t)row * DIM);
  float4 xa = x4[lane * 2], xb = x4[lane * 2 + 1];
  double bestd = 1e300; int besti = 0x7FFFFFFF;
  #pragma unroll
  for (int part = 0; part < 2; ++part) {
    unsigned long long mm = part == 0 ? m0 : m1;
    int cv = part == 0 ? cv0 : cv1;
    while (mm) {
      int src = __ffsll(mm) - 1; mm &= mm - 1;
      int idx = __shfl(cv, src, 64);
      const float4* c4 = (const float4*)(Cb + (size_t)idx * DIM);
      float4 ca = c4[lane * 2], cb = c4[lane * 2 + 1];
      double dt = (double)xa.x*ca.x + (double)xa.y*ca.y + (double)xa.z*ca.z + (double)xa.w*ca.w
                + (double)xb.x*cb.x + (double)xb.y*cb.y + (double)xb.z*cb.z + (double)xb.w*cb.w;
      double cc = (double)ca.x*ca.x + (double)ca.y*ca.y + (double)ca.z*ca.z + (double)ca.w*ca.w
                + (double)cb.x*cb.x + (double)cb.y*cb.y + (double)cb.z*cb.z + (double)cb.w*cb.w;
      double sdist = cc - 2.0 * dt;           // x2 omitted: per-row constant
      #pragma unroll
      for (int off = 32; off; off >>= 1) sdist += __shfl_down(sdist, off, 64);
      if (lane == 0 && (sdist < bestd || (sdist == bestd && idx < besti))) { bestd = sdist; besti = idx; }
    }
  }
  if (lane == 0) idx_out[row] = (float)besti;
}

// ---- fallback path: quantized = inputs (runs LAST; overwrites scratch) -----
__global__ void vq_copy(const float* __restrict__ in, float* __restrict__ out, int n4) {
  int i = blockIdx.x * blockDim.x + threadIdx.x;
  int st = gridDim.x * blockDim.x;
  const float4* s = (const float4*)in;
  float4* d = (float4*)out;
  for (; i < n4; i += st) d[i] = s[i];
}

extern "C" void kernel_launch(void* const* d_in, const int* in_sizes, int n_in,
                              void* d_out, int out_size, void* d_ws, size_t ws_size,
                              hipStream_t stream) {
  const float* X  = (const float*)d_in[0];
  const float* Cb = (const float*)d_in[1];
  float* out = (float*)d_out;
  float* idx_out = out + (size_t)NTOK * DIM;

  // scratch need: c2 32KB + Xq 16MB + Cq 4MB + cand 12MB = 33,587,200 B
  const size_t NEED = 32768ull + 16777216ull + 4194304ull + 12582912ull;
  if (ws_size >= NEED) {
    // big-ws path: all scratch in d_ws; copy fused with prep; no final copy.
    float*         c2   = (float*)d_ws;
    unsigned char* Xq   = (unsigned char*)d_ws + 32768;
    unsigned char* Cq   = Xq + 16777216;
    int*           cand = (int*)(Cq + 4194304);
    vq_copyprep8<<<NTOK / 4, 256, 0, stream>>>(X, out, Xq, NTOK);
    vq_prep8<<<KCODES / 4, 256, 0, stream>>>(Cb, Cq, c2, KCODES);
    vq_main<<<NTOK / 64, 256, 0, stream>>>(Xq, Cq, c2, cand);
    vq_refine<<<NTOK / 4, 256, 0, stream>>>(X, Cb, cand, idx_out);
  } else {
    // fallback: scratch carved from d_out (r15 path), copy runs last.
    unsigned char* Xq   = (unsigned char*)out;                // [N][512] fp8
    unsigned char* Cq   = (unsigned char*)(out + 4194304);    // [K][512] fp8
    int*           cand = (int*)(out + 5242880);              // [N][96]
    float*         c2   = (float*)d_ws;                       // [K]
    vq_prep8<<<KCODES / 4, 256, 0, stream>>>(Cb, Cq, c2, KCODES);
    vq_prep8<<<NTOK / 4, 256, 0, stream>>>(X, Xq, nullptr, NTOK);
    vq_main<<<NTOK / 64, 256, 0, stream>>>(Xq, Cq, c2, cand);
    vq_refine<<<NTOK / 4, 256, 0, stream>>>(X, Cb, cand, idx_out);
    vq_copy<<<2048, 256, 0, stream>>>(X, out, NTOK * DIM / 4);
  }
}

// Round 17
// 228.269 us; speedup vs baseline: 1.4112x; 1.0373x over previous
//
#include <hip/hip_runtime.h>
#include <hip/hip_bf16.h>

// VQ argmin via MX-scaled fp8 (e4m3, scale=1.0) K=128 MFMA filter + exact
// fp64 refine. Round 17: A-fragments are loop-invariant (depend only on
// kp,rf) -> cache all 8 in registers (64 VGPR), drop the As LDS buffer.
// Cuts per-wave LDS reads 12->8 b128/phase and LDS to 48K/block.
// __launch_bounds__(256,1) gives the allocator a 512-reg budget; demand
// ~170 still allows the LDS-limited 2 waves/EU occupancy (no real loss).
// B-side layout/protocol byte-identical to r13/r15/r16 (proven).

constexpr int NTOK = 32768, DIM = 512, KCODES = 8192;
constexpr float MARGIN = 20.0f;

using ffrag = __attribute__((ext_vector_type(4))) float;   // 4 f32 acc
using i32x4 = __attribute__((ext_vector_type(4))) int;
using i32x8 = __attribute__((ext_vector_type(8))) int;

#define GLD_LDS16(g, l)                                                        \
  __builtin_amdgcn_global_load_lds(                                            \
      (const __attribute__((address_space(1))) void*)(g),                      \
      (__attribute__((address_space(3))) void*)(l), 16, 0, 0)
#define VMW(N) asm volatile("s_waitcnt vmcnt(" #N ")" ::: "memory")

// ---- f32 -> fp8 e4m3fn, explicit RNE ---------------------------------------
__device__ __forceinline__ unsigned char f2e4m3(float x) {
  unsigned u = __float_as_uint(x);
  unsigned s = (u >> 24) & 0x80u;
  float ax = fabsf(x);
  if (ax < 0.015625f) {
    int q = (int)rintf(ax * 512.0f);
    return (unsigned char)(s | (unsigned)q);
  }
  int e = (int)((u >> 23) & 0xFF) - 127;
  float m = __uint_as_float((u & 0x7FFFFFu) | 0x3F800000u);
  int r = (int)rintf(m * 8.0f);
  if (r == 16) { r = 8; ++e; }
  if (e > 8) { e = 8; r = 15; }
  return (unsigned char)(s | ((unsigned)(e + 7) << 3) | (unsigned)(r - 8));
}

// ---- convert fp32 rows -> fp8, optional sum-of-squares ---------------------
__global__ void vq_prep8(const float* __restrict__ src, unsigned char* __restrict__ dst,
                         float* __restrict__ sq, int rows) {
  int w = (blockIdx.x * blockDim.x + threadIdx.x) >> 6;
  int lane = threadIdx.x & 63;
  if (w >= rows) return;
  const float4* r4 = (const float4*)(src + (size_t)w * DIM);
  float4 a = r4[lane * 2], b = r4[lane * 2 + 1];
  union { unsigned char c[8]; uint2 v; } o;
  o.c[0]=f2e4m3(a.x); o.c[1]=f2e4m3(a.y); o.c[2]=f2e4m3(a.z); o.c[3]=f2e4m3(a.w);
  o.c[4]=f2e4m3(b.x); o.c[5]=f2e4m3(b.y); o.c[6]=f2e4m3(b.z); o.c[7]=f2e4m3(b.w);
  *(uint2*)(dst + (size_t)w * DIM + lane * 8) = o.v;
  if (sq != nullptr) {
    float s = a.x*a.x + a.y*a.y + a.z*a.z + a.w*a.w
            + b.x*b.x + b.y*b.y + b.z*b.z + b.w*b.w;
    #pragma unroll
    for (int off = 32; off; off >>= 1) s += __shfl_down(s, off, 64);
    if (lane == 0) sq[w] = s;
  }
}

// ---- fused: out = src (copy) AND dst = fp8(src) ----------------------------
__global__ void vq_copyprep8(const float* __restrict__ src, float* __restrict__ outc,
                             unsigned char* __restrict__ dst, int rows) {
  int w = (blockIdx.x * blockDim.x + threadIdx.x) >> 6;
  int lane = threadIdx.x & 63;
  if (w >= rows) return;
  const float4* r4 = (const float4*)(src + (size_t)w * DIM);
  float4 a = r4[lane * 2], b = r4[lane * 2 + 1];
  float4* o4 = (float4*)(outc + (size_t)w * DIM);
  o4[lane * 2] = a; o4[lane * 2 + 1] = b;
  union { unsigned char c[8]; uint2 v; } o;
  o.c[0]=f2e4m3(a.x); o.c[1]=f2e4m3(a.y); o.c[2]=f2e4m3(a.z); o.c[3]=f2e4m3(a.w);
  o.c[4]=f2e4m3(b.x); o.c[5]=f2e4m3(b.y); o.c[6]=f2e4m3(b.z); o.c[7]=f2e4m3(b.w);
  *(uint2*)(dst + (size_t)w * DIM + lane * 8) = o.v;
}

// ---- fused MX-fp8 K=128 MFMA distance + best-3 + candidate emission --------
// Block: 256 thr (4 waves: wr,wc in {0,1}), 64 rows x FULL 8192 codes.
// A-frags cached in regs (aC[4][2], loaded once from global). Slab ring-3
// [128 cols][8 units of 16B], unit stored at u^(col&7) (proven r13 layout).
__launch_bounds__(256, 1)
__global__ void vq_main(const unsigned char* __restrict__ Xq,
                        const unsigned char* __restrict__ Cq,
                        const float* __restrict__ c2g, int* __restrict__ cand) {
  __shared__ __align__(16) unsigned char Bs[3][16384];     // 48 KiB ring-3
  const int tid = threadIdx.x, lane = tid & 63;
  const int wid = tid >> 6, wr = wid >> 1, wc = wid & 1;
  const int row0 = blockIdx.x * 64;
  const int l15 = lane & 15, l4 = lane >> 4;

  // ---------- prologue: A-frag register cache + slabs 0,1 ----------
  i32x8 aC[4][2];
  #pragma unroll
  for (int kp = 0; kp < 4; ++kp)
    #pragma unroll
    for (int rf = 0; rf < 2; ++rf) {
      int rA = wr * 32 + rf * 16 + l15;
      aC[kp][rf] = *(const i32x8*)(Xq + (size_t)(row0 + rA) * DIM +
                                   kp * 128 + l4 * 32);
    }
  #pragma unroll
  for (int t0 = 0; t0 < 2; ++t0) {
    #pragma unroll
    for (int i = 0; i < 4; ++i) {
      int p = i * 256 + tid, c = p >> 3, u = p & 7;
      GLD_LDS16(Cq + (size_t)c * DIM + t0 * 128 + ((u ^ (c & 7)) << 4),
                &Bs[t0][0] + p * 16);
    }
  }
  VMW(4);                                  // aC + slab0 landed (slab1 flying)
  __builtin_amdgcn_s_barrier();

  // ---------- hoisted per-thread address state ----------
  int bLo[4], bHi[4];
  #pragma unroll
  for (int cf = 0; cf < 4; ++cf) {
    int rB = wc * 64 + cf * 16 + l15, sw = rB & 7;
    bLo[cf] = rB * 128 + (((2 * l4) ^ sw) << 4);
    bHi[cf] = rB * 128 + (((2 * l4 + 1) ^ sw) << 4);
  }
  const int cS = tid >> 3, uS = tid & 7;
  const unsigned char* gsrc = Cq + cS * 512 + ((uS ^ (cS & 7)) << 4) + 256; // ts=2
  const float* c2p = c2g + wc * 64 + l15;
  unsigned char* ldst = &Bs[0][0] + tid * 16;
  const unsigned char* BsP = &Bs[0][0];

  unsigned b0k[2][4], b1k[2][4], b2k[2][4];
  #pragma unroll
  for (int rf = 0; rf < 2; ++rf)
    #pragma unroll
    for (int rg = 0; rg < 4; ++rg) {
      b0k[rf][rg] = 0xFFFFFFFFu; b1k[rf][rg] = 0xFFFFFFFFu; b2k[rf][rg] = 0xFFFFFFFFu;
    }
  ffrag acc[2][4];
  float c2v[4];

// One phase. KP/RS/SS/GSTEP/VMN are literals; CT is a runtime int.
#define PH(KP, RS, SS, CT, STG, GSTEP, VMN)                                    \
  {                                                                            \
    if (KP == 2) {                                                             \
      c2v[0] = c2p[0];  c2v[1] = c2p[16];                                      \
      c2v[2] = c2p[32]; c2v[3] = c2p[48];                                      \
      c2p += 128;                                                              \
    }                                                                          \
    if (STG) {                                                                 \
      GLD_LDS16(gsrc,         ldst + (SS) * 16384 + 0);                        \
      GLD_LDS16(gsrc + 16384, ldst + (SS) * 16384 + 4096);                     \
      GLD_LDS16(gsrc + 32768, ldst + (SS) * 16384 + 8192);                     \
      GLD_LDS16(gsrc + 49152, ldst + (SS) * 16384 + 12288);                    \
      gsrc += (GSTEP);                                                         \
    }                                                                          \
    i32x8 bF[4];                                                               \
    _Pragma("unroll")                                                          \
    for (int cf = 0; cf < 4; ++cf) {                                           \
      i32x4 lo = *(const i32x4*)(BsP + (RS) * 16384 + bLo[cf]);                \
      i32x4 hi = *(const i32x4*)(BsP + (RS) * 16384 + bHi[cf]);                \
      bF[cf] = __builtin_shufflevector(lo, hi, 0, 1, 2, 3, 4, 5, 6, 7);        \
    }                                                                          \
    __builtin_amdgcn_s_setprio(1);                                             \
    _Pragma("unroll")                                                          \
    for (int rf = 0; rf < 2; ++rf)                                             \
      _Pragma("unroll")                                                        \
      for (int cf = 0; cf < 4; ++cf) {                                         \
        if (KP == 0) {                                                         \
          ffrag z = {0.f, 0.f, 0.f, 0.f};                                      \
          acc[rf][cf] = __builtin_amdgcn_mfma_scale_f32_16x16x128_f8f6f4(      \
              aC[KP][rf], bF[cf], z, 0, 0, 0, 0x7F7F7F7F, 0, 0x7F7F7F7F);      \
        } else {                                                               \
          acc[rf][cf] = __builtin_amdgcn_mfma_scale_f32_16x16x128_f8f6f4(      \
              aC[KP][rf], bF[cf], acc[rf][cf], 0, 0, 0, 0x7F7F7F7F, 0,         \
              0x7F7F7F7F);                                                     \
        }                                                                      \
      }                                                                        \
    __builtin_amdgcn_s_setprio(0);                                             \
    if (KP == 3) {                                                             \
      _Pragma("unroll")                                                        \
      for (int rf = 0; rf < 2; ++rf)                                           \
        _Pragma("unroll")                                                      \
        for (int rg = 0; rg < 4; ++rg) {                                       \
          _Pragma("unroll")                                                    \
          for (int cf = 0; cf < 4; ++cf) {                                     \
            float d = fmaf(-2.0f, acc[rf][cf][rg], c2v[cf] + 2048.0f);         \
            unsigned k = (__float_as_uint(d) & 0xFFFFFF00u) |                  \
                         (unsigned)(((CT) << 2) | cf);                         \
            unsigned lo0 = min(b0k[rf][rg], k), hi0 = max(b0k[rf][rg], k);     \
            b0k[rf][rg] = lo0;                                                 \
            unsigned lo1 = min(b1k[rf][rg], hi0), hi1 = max(b1k[rf][rg], hi0); \
            b1k[rf][rg] = lo1;                                                 \
            b2k[rf][rg] = min(b2k[rf][rg], hi1);                               \
          }                                                                    \
        }                                                                      \
    }                                                                          \
    VMW(VMN);                                                                  \
    asm volatile("s_waitcnt lgkmcnt(0)" ::: "memory");                         \
    __builtin_amdgcn_s_barrier();                                              \
  }

  // main loop: 21 x 12 phases (3 cts each); slot/kp pattern period = 12
  for (int c3 = 0; c3 < 21; ++c3) {
    const int ct0 = c3 * 3;
    PH(0, 0, 2, ct0,     1, 128,   4)
    PH(1, 1, 0, ct0,     1, 65152, 4)
    PH(2, 2, 1, ct0,     1, 128,   4)
    PH(3, 0, 2, ct0,     1, 128,   4)
    PH(0, 1, 0, ct0 + 1, 1, 128,   4)
    PH(1, 2, 1, ct0 + 1, 1, 65152, 4)
    PH(2, 0, 2, ct0 + 1, 1, 128,   4)
    PH(3, 1, 0, ct0 + 1, 1, 128,   4)
    PH(0, 2, 1, ct0 + 2, 1, 128,   4)
    PH(1, 0, 2, ct0 + 2, 1, 65152, 4)
    PH(2, 1, 0, ct0 + 2, 1, 128,   4)
    PH(3, 2, 1, ct0 + 2, 1, 128,   4)
  }
  // tail: ct = 63 (phases t=252..255; stages ts=254,255 then drain)
  {
    const int ctT = 63;
    PH(0, 0, 2, ctT, 1, 128, 4)
    PH(1, 1, 0, ctT, 1, 0,   4)
    PH(2, 2, 1, ctT, 0, 0,   0)
    PH(3, 0, 2, ctT, 0, 0,   0)
  }
#undef PH

  // per-row min across 16 l15-lanes; cross-wc merge via LDS (overlay on Bs)
  unsigned* dstar = (unsigned*)&Bs[0][0];   // [2][64]
  unsigned gmin[2][4];
  #pragma unroll
  for (int rf = 0; rf < 2; ++rf)
    #pragma unroll
    for (int rg = 0; rg < 4; ++rg) {
      unsigned g = b0k[rf][rg];
      #pragma unroll
      for (int m = 1; m < 16; m <<= 1)
        g = min(g, (unsigned)__shfl_xor((int)g, m, 64));
      gmin[rf][rg] = g;
      if (l15 == 0) dstar[wc * 64 + wr * 32 + rf * 16 + l4 * 4 + rg] = g;
    }
  __syncthreads();
  #pragma unroll
  for (int rf = 0; rf < 2; ++rf)
    #pragma unroll
    for (int rg = 0; rg < 4; ++rg) {
      int rl = wr * 32 + rf * 16 + l4 * 4 + rg;
      unsigned gg = min(gmin[rf][rg], dstar[(wc ^ 1) * 64 + rl]);
      float ds = __uint_as_float(gg & 0xFFFFFF00u);
      unsigned thr = __float_as_uint(ds + MARGIN);
      int base = (row0 + rl) * 96 + wc * 48 + l15 * 3;
      unsigned kk0 = b0k[rf][rg], kk1 = b1k[rf][rg], kk2 = b2k[rf][rg];
      int c0 = (int)((kk0 >> 2) & 63u) * 128 + wc * 64 + (int)(kk0 & 3u) * 16 + l15;
      int c1 = (int)((kk1 >> 2) & 63u) * 128 + wc * 64 + (int)(kk1 & 3u) * 16 + l15;
      int c2i = (int)((kk2 >> 2) & 63u) * 128 + wc * 64 + (int)(kk2 & 3u) * 16 + l15;
      cand[base + 0] = (kk0 <= thr) ? c0 : -1;
      cand[base + 1] = (kk1 <= thr) ? c1 : -1;
      cand[base + 2] = (kk2 <= thr) ? c2i : -1;
    }
}

// ---- exact fp64 refine over candidate set (one wave per row, 96 slots) -----
__global__ void vq_refine(const float* __restrict__ X, const float* __restrict__ Cb,
                          const int* __restrict__ cand, float* __restrict__ idx_out) {
  int row = (blockIdx.x * blockDim.x + threadIdx.x) >> 6;
  int lane = threadIdx.x & 63;
  if (row >= NTOK) return;
  int cv0 = cand[row * 96 + lane];
  int cv1 = (lane < 32) ? cand[row * 96 + 64 + lane] : -1;
  unsigned long long m0 = __ballot(cv0 >= 0);
  unsigned long long m1 = __ballot(cv1 >= 0);
  if (__popcll(m0) + __popcll(m1) == 1) {
    int idx;
    if (m0) idx = __shfl(cv0, __ffsll(m0) - 1, 64);
    else    idx = __shfl(cv1, __ffsll(m1) - 1, 64);
    if (lane == 0) idx_out[row] = (float)idx;
    return;
  }
  const float4* x4 = (const float4*)(X + (size_t)row * DIM);
  float4 xa = x4[lane * 2], xb = x4[lane * 2 + 1];
  double bestd = 1e300; int besti = 0x7FFFFFFF;
  #pragma unroll
  for (int part = 0; part < 2; ++part) {
    unsigned long long mm = part == 0 ? m0 : m1;
    int cv = part == 0 ? cv0 : cv1;
    while (mm) {
      int src = __ffsll(mm) - 1; mm &= mm - 1;
      int idx = __shfl(cv, src, 64);
      const float4* c4 = (const float4*)(Cb + (size_t)idx * DIM);
      float4 ca = c4[lane * 2], cb = c4[lane * 2 + 1];
      double dt = (double)xa.x*ca.x + (double)xa.y*ca.y + (double)xa.z*ca.z + (double)xa.w*ca.w
                + (double)xb.x*cb.x + (double)xb.y*cb.y + (double)xb.z*cb.z + (double)xb.w*cb.w;
      double cc = (double)ca.x*ca.x + (double)ca.y*ca.y + (double)ca.z*ca.z + (double)ca.w*ca.w
                + (double)cb.x*cb.x + (double)cb.y*cb.y + (double)cb.z*cb.z + (double)cb.w*cb.w;
      double sdist = cc - 2.0 * dt;           // x2 omitted: per-row constant
      #pragma unroll
      for (int off = 32; off; off >>= 1) sdist += __shfl_down(sdist, off, 64);
      if (lane == 0 && (sdist < bestd || (sdist == bestd && idx < besti))) { bestd = sdist; besti = idx; }
    }
  }
  if (lane == 0) idx_out[row] = (float)besti;
}

// ---- fallback path: quantized = inputs (runs LAST; overwrites scratch) -----
__global__ void vq_copy(const float* __restrict__ in, float* __restrict__ out, int n4) {
  int i = blockIdx.x * blockDim.x + threadIdx.x;
  int st = gridDim.x * blockDim.x;
  const float4* s = (const float4*)in;
  float4* d = (float4*)out;
  for (; i < n4; i += st) d[i] = s[i];
}

extern "C" void kernel_launch(void* const* d_in, const int* in_sizes, int n_in,
                              void* d_out, int out_size, void* d_ws, size_t ws_size,
                              hipStream_t stream) {
  const float* X  = (const float*)d_in[0];
  const float* Cb = (const float*)d_in[1];
  float* out = (float*)d_out;
  float* idx_out = out + (size_t)NTOK * DIM;

  // scratch need: c2 32KB + Xq 16MB + Cq 4MB + cand 12MB = 33,587,200 B
  const size_t NEED = 32768ull + 16777216ull + 4194304ull + 12582912ull;
  if (ws_size >= NEED) {
    // big-ws path: all scratch in d_ws; copy fused with prep; no final copy.
    float*         c2   = (float*)d_ws;
    unsigned char* Xq   = (unsigned char*)d_ws + 32768;
    unsigned char* Cq   = Xq + 16777216;
    int*           cand = (int*)(Cq + 4194304);
    vq_copyprep8<<<NTOK / 4, 256, 0, stream>>>(X, out, Xq, NTOK);
    vq_prep8<<<KCODES / 4, 256, 0, stream>>>(Cb, Cq, c2, KCODES);
    vq_main<<<NTOK / 64, 256, 0, stream>>>(Xq, Cq, c2, cand);
    vq_refine<<<NTOK / 4, 256, 0, stream>>>(X, Cb, cand, idx_out);
  } else {
    // fallback: scratch carved from d_out (r15 path), copy runs last.
    unsigned char* Xq   = (unsigned char*)out;                // [N][512] fp8
    unsigned char* Cq   = (unsigned char*)(out + 4194304);    // [K][512] fp8
    int*           cand = (int*)(out + 5242880);              // [N][96]
    float*         c2   = (float*)d_ws;                       // [K]
    vq_prep8<<<KCODES / 4, 256, 0, stream>>>(Cb, Cq, c2, KCODES);
    vq_prep8<<<NTOK / 4, 256, 0, stream>>>(X, Xq, nullptr, NTOK);
    vq_main<<<NTOK / 64, 256, 0, stream>>>(Xq, Cq, c2, cand);
    vq_refine<<<NTOK / 4, 256, 0, stream>>>(X, Cb, cand, idx_out);
    vq_copy<<<2048, 256, 0, stream>>>(X, out, NTOK * DIM / 4);
  }
}